// Round 13
// baseline (433.118 us; speedup 1.0000x reference)
//
#include <hip/hip_runtime.h>
#include <stdint.h>

using u16 = unsigned short;
typedef u16   u16x8  __attribute__((ext_vector_type(8)));
typedef u16   u16x4  __attribute__((ext_vector_type(4)));
typedef short bf16x8 __attribute__((ext_vector_type(8)));
typedef float f32x4  __attribute__((ext_vector_type(4)));

#define DEVI static __device__ __forceinline__

// sizes (fixed): B=16, C=1024, HW=48*48=2304, MID=256, N3=768
// attention: JBLK=32, 72 j-tiles, 4 j-quarters of 18; q-tile 64

DEVI u16 f2bf(float f) {                       // RNE float->bf16
    union { float f; uint32_t u; } v; v.f = f;
    return (u16)((v.u + 0x7fffu + ((v.u >> 16) & 1u)) >> 16);
}
DEVI float bf2f(u16 u) {
    union { uint32_t u; float f; } v; v.u = (uint32_t)u << 16; return v.f;
}

DEVI f32x4 mfma16(bf16x8 a, bf16x8 b, f32x4 c) {
    return __builtin_amdgcn_mfma_f32_16x16x32_bf16(a, b, c, 0, 0, 0);
}

DEVI float exp2fast(float x) { return __builtin_amdgcn_exp2f(x); }

// async global->LDS, 16B per lane; LDS dest = wave-uniform base + lane*16
DEVI void gll16(const u16* g, u16* l) {
    __builtin_amdgcn_global_load_lds(
        (const __attribute__((address_space(1))) void*)g,
        (__attribute__((address_space(3))) void*)l, 16, 0, 0);
}

// LDS tile readers; layout: [row][8*spr u16], logical slot s stored at s^(row&7)
DEVI bf16x8 frag64(const u16* base, int row, int slot) {   // 64 u16 per row (8 slots)
    return *(const bf16x8*)(base + row * 64 + ((slot ^ (row & 7)) << 3));
}
DEVI bf16x8 frag256(const u16* base, int row, int slot) {  // 256 u16 per row (32 slots)
    return *(const bf16x8*)(base + row * 256 + ((slot ^ (row & 7)) << 3));
}
// 32-u16 rows (4 slots of 8): slot s stored at s^((row>>1)&3)
DEVI bf16x8 frag32(const u16* base, int row, int slot) {
    return *(const bf16x8*)(base + row * 32 + ((slot ^ ((row >> 1) & 3)) << 3));
}

// ---------------------------------------------------------------- prep
__global__ __launch_bounds__(256) void k_prep(
    const float* __restrict__ Wf, const float* __restrict__ bfp,
    const float* __restrict__ gf, const float* __restrict__ btf,
    const float* __restrict__ mf, const float* __restrict__ vf,
    const float* __restrict__ Wg, const float* __restrict__ bg,
    const float* __restrict__ gg, const float* __restrict__ btg,
    const float* __restrict__ mg, const float* __restrict__ vg,
    const float* __restrict__ Wh, const float* __restrict__ bh,
    const float* __restrict__ Wv,
    u16* __restrict__ W3bf, u16* __restrict__ Wvbf,
    float* __restrict__ alpha, float* __restrict__ beta)
{
    int tid = blockIdx.x * 256 + threadIdx.x;
    if (tid < 768 * 1024) {
        int n = tid >> 10, k = tid & 1023;
        float w = (n < 256) ? Wf[n * 1024 + k]
                : (n < 512) ? Wg[(n - 256) * 1024 + k]
                            : Wh[(n - 512) * 1024 + k];
        W3bf[tid] = f2bf(w);
    } else if (tid < 768 * 1024 + 256 * 1024) {
        int i = tid - 768 * 1024;
        Wvbf[i] = f2bf(Wv[i]);
    } else if (tid < 768 * 1024 + 256 * 1024 + 768) {
        int n = tid - (768 * 1024 + 256 * 1024);
        const float EPS = 1e-5f;
        const float SC  = 0.0625f * 1.4426950408889634f;  // mid^-0.5 * log2(e)
        float a, be;
        if (n < 256) {
            float inv = gf[n] / sqrtf(vf[n] + EPS);
            a  = inv * SC;
            be = (bfp[n] * inv + btf[n] - mf[n] * inv) * SC;
        } else if (n < 512) {
            int m = n - 256;
            float inv = gg[m] / sqrtf(vg[m] + EPS);
            a  = inv;
            be = bg[m] * inv + btg[m] - mg[m] * inv;
        } else { a = 1.0f; be = bh[n - 512]; }
        alpha[n] = a; beta[n] = be;
    }
}

// ---------------------------------------------------------------- x -> xT (bf16)
__global__ __launch_bounds__(256) void k_transpose(
    const float* __restrict__ x, u16* __restrict__ xT)
{
    __shared__ __align__(16) u16 tile[64 * 68];
    const int t  = threadIdx.x;
    const int it = blockIdx.x;   // 0..35
    const int ct = blockIdx.y;   // 0..15
    const int b  = blockIdx.z;   // 0..15
    const size_t xbase = ((size_t)(b * 1024 + ct * 64)) * 2304 + (size_t)it * 64;
    #pragma unroll
    for (int q = 0; q < 4; ++q) {
        int idx = q * 256 + t;
        int cl = idx >> 4, i4 = idx & 15;
        float4 v = *(const float4*)(x + xbase + (size_t)cl * 2304 + i4 * 4);
        tile[(i4 * 4 + 0) * 68 + cl] = f2bf(v.x);
        tile[(i4 * 4 + 1) * 68 + cl] = f2bf(v.y);
        tile[(i4 * 4 + 2) * 68 + cl] = f2bf(v.z);
        tile[(i4 * 4 + 3) * 68 + cl] = f2bf(v.w);
    }
    __syncthreads();
    const size_t obase = ((size_t)(b * 2304 + it * 64)) * 1024 + (size_t)ct * 64;
    #pragma unroll
    for (int q = 0; q < 4; ++q) {
        int idx = q * 256 + t;
        int il = idx >> 4, c4 = idx & 15;
        u16x4 w = *(const u16x4*)(&tile[il * 68 + c4 * 4]);
        *(u16x4*)(xT + obase + (size_t)il * 1024 + c4 * 4) = w;
    }
}

// ---------------------------------------------------------------- h -> HT
__global__ __launch_bounds__(256) void k_htrans(
    const u16* __restrict__ FGH, u16* __restrict__ HT)
{
    __shared__ __align__(16) u16 tile[64 * 68];
    const int t  = threadIdx.x;
    const int jt = blockIdx.x;   // 0..35
    const int mt = blockIdx.y;   // 0..3
    const int b  = blockIdx.z;
    const u16* src = FGH + ((size_t)b * 2304 + jt * 64) * 768 + 512 + mt * 64;
    #pragma unroll
    for (int q = 0; q < 4; ++q) {
        int idx = q * 256 + t;
        int j = idx >> 4, m4 = idx & 15;
        u16x4 v = *(const u16x4*)(src + (size_t)j * 768 + m4 * 4);
        tile[(m4 * 4 + 0) * 68 + j] = v[0];
        tile[(m4 * 4 + 1) * 68 + j] = v[1];
        tile[(m4 * 4 + 2) * 68 + j] = v[2];
        tile[(m4 * 4 + 3) * 68 + j] = v[3];
    }
    __syncthreads();
    u16* dst = HT + ((size_t)b * 256 + mt * 64) * 2304 + (size_t)jt * 64;
    #pragma unroll
    for (int q = 0; q < 4; ++q) {
        int idx = q * 256 + t;
        int m = idx >> 4, j4 = idx & 15;
        u16x4 w = *(const u16x4*)(&tile[m * 68 + j4 * 4]);
        *(u16x4*)(dst + (size_t)m * 2304 + j4 * 4) = w;
    }
}

// ---------------------------------------------------------------- NT GEMM 128x128, BK=64
// double-buffered global_load_lds prefetch (T3-minimal 2-phase)
template<int MODE>
__global__ __launch_bounds__(256) void k_gemm(
    const u16* __restrict__ A, const u16* __restrict__ Bm, const int K,
    u16* __restrict__ Cbf, const float* __restrict__ alpha, const float* __restrict__ beta,
    float* __restrict__ Cf, const float* __restrict__ bias, const float* __restrict__ resid)
{
    __shared__ __align__(16) u16 As[2][128 * 64];
    __shared__ __align__(16) u16 Bs[2][128 * 64];
    const int t = threadIdx.x;
    const int lane = t & 63, wave = t >> 6;
    const int wu = __builtin_amdgcn_readfirstlane(wave);
    const int g = lane >> 4, l15 = lane & 15;
    const int wr = wave >> 1, wc = wave & 1;
    const int m0 = blockIdx.x * 128, n0 = blockIdx.y * 128;
    const int b  = blockIdx.z;

    const u16* Ag = A + (size_t)m0 * K;
    const u16* Bg = (MODE == 0) ? (Bm + (size_t)n0 * K)
                                : (Bm + ((size_t)b * 2304 + n0) * K);

    auto stage = [&](int buf, int ks) {
        #pragma unroll
        for (int i = 0; i < 4; ++i) {
            int c = i * 256 + wu * 64 + lane;
            int row = c >> 3, p = c & 7, s = p ^ (row & 7);
            size_t go = (size_t)row * K + ks * 64 + s * 8;
            gll16(Ag + go, &As[buf][(i * 256 + wu * 64) * 8]);
            gll16(Bg + go, &Bs[buf][(i * 256 + wu * 64) * 8]);
        }
    };

    f32x4 acc[4][4] = {};
    const int nks = K >> 6;
    stage(0, 0);
    asm volatile("s_waitcnt vmcnt(0)");
    __syncthreads();
    int cur = 0;
    for (int ks = 0; ks < nks; ++ks) {
        if (ks + 1 < nks) stage(cur ^ 1, ks + 1);
        const u16* as = &As[cur][0];
        const u16* bs = &Bs[cur][0];
        __builtin_amdgcn_s_setprio(1);
        #pragma unroll
        for (int kk = 0; kk < 2; ++kk) {
            const int slot = kk * 4 + g;
            bf16x8 af[4], bfv[4];
            #pragma unroll
            for (int f = 0; f < 4; ++f) af[f]  = frag64(as, wr * 64 + f * 16 + l15, slot);
            #pragma unroll
            for (int f = 0; f < 4; ++f) bfv[f] = frag64(bs, wc * 64 + f * 16 + l15, slot);
            #pragma unroll
            for (int fm = 0; fm < 4; ++fm)
                #pragma unroll
                for (int fn = 0; fn < 4; ++fn)
                    acc[fm][fn] = mfma16(af[fm], bfv[fn], acc[fm][fn]);
        }
        __builtin_amdgcn_s_setprio(0);
        asm volatile("s_waitcnt vmcnt(0)");
        __syncthreads();
        cur ^= 1;
    }

    if (MODE == 0) {
        #pragma unroll
        for (int fn = 0; fn < 4; ++fn) {
            const int n = n0 + wc * 64 + fn * 16 + l15;
            const float al = alpha[n], be = beta[n];
            const bool dorelu = (n < 512);
            #pragma unroll
            for (int fm = 0; fm < 4; ++fm)
                #pragma unroll
                for (int r = 0; r < 4; ++r) {
                    const int row = m0 + wr * 64 + fm * 16 + 4 * g + r;
                    float y = acc[fm][fn][r] * al + be;
                    if (dorelu) y = fmaxf(y, 0.0f);
                    Cbf[(size_t)row * 768 + n] = f2bf(y);
                }
        }
    } else {
        const size_t ob = (size_t)b * 1024 * 2304;
        #pragma unroll
        for (int fm = 0; fm < 4; ++fm)
            #pragma unroll
            for (int r = 0; r < 4; ++r) {
                const int row = m0 + wr * 64 + fm * 16 + 4 * g + r;   // c
                const float bb = bias[row];
                #pragma unroll
                for (int fn = 0; fn < 4; ++fn) {
                    const int n = n0 + wc * 64 + fn * 16 + l15;        // i
                    const size_t o = ob + (size_t)row * 2304 + n;
                    Cf[o] = acc[fm][fn][r] + bb + resid[o];
                }
            }
    }
}

// ---------------------------------------------------------------- fused attention v5
// grid (qt=36, jq=4, b=16); 4 waves = 2 row-groups (rg, 32q) x 2 m-halves (mh, 128m).
// v5: QK is WAVE-LOCAL — each wave computes the full S[32q][32j] for its rows
// (duplicating its mh-twin's QK, +5us of MFMA pipe total) so the P tile is
// private per wave: softmax+P-write+PV need NO mid-iter barrier (same-wave
// LDS write->read is ordered by compiler lgkmcnt). Only the end-of-iter
// vmcnt+barrier (K/V buffer protection) remains -> waves drift within the
// iter and fill each other's pipe gaps (r12 lesson: all pipes <40% busy,
// phase-lockstep was the residual serializer).
// No-max softmax (anchor 0), row-sum via ones-MFMA, dbuf K/V prefetch.
// NOTE: single-arg launch_bounds — second arg N caps VGPRs at 256/N (r2/r3 spills).
__global__ __launch_bounds__(256) void k_attn(
    const u16* __restrict__ FGH, const u16* __restrict__ HT,
    u16* __restrict__ Opart, float* __restrict__ statl)
{
    __shared__ __align__(16) u16 Ks[2][32 * 256];   // 2x16 KB [j][k]
    __shared__ __align__(16) u16 Vt[2][256 * 32];   // 2x16 KB [m][j]
    __shared__ __align__(16) u16 Ps[4][32 * 32];    //   8 KB per-WAVE P (32q x 32j)
    const int t = threadIdx.x;
    const int lane = t & 63, wave = t >> 6;
    const int wu = __builtin_amdgcn_readfirstlane(wave);
    const int rg = wu >> 1, mh = wu & 1;
    const int g = lane >> 4, l15 = lane & 15;
    const int qt = blockIdx.x, jq = blockIdx.y, b = blockIdx.z;

    // Q rows of this wave: qt*64 + rg*32 + fm*16 + l15
    const u16* Qg = FGH + ((size_t)b * 2304 + qt * 64 + rg * 32) * 768;
    bf16x8 qf[2][8];
    #pragma unroll
    for (int fm = 0; fm < 2; ++fm)
        #pragma unroll
        for (int kk = 0; kk < 8; ++kk)
            qf[fm][kk] = *(const bf16x8*)(Qg + (size_t)(fm * 16 + l15) * 768 + kk * 32 + g * 8);

    const u16* Kg0 = FGH + (size_t)b * 2304 * 768 + 256;   // keys [j][k]
    const u16* Hg0 = HT + (size_t)b * 256 * 2304;          // V^T [m][j]
    u16* Pw = &Ps[wu][0];                                  // wave-private P

    bf16x8 ones;
    #pragma unroll
    for (int e = 0; e < 8; ++e) ones[e] = (short)0x3F80;   // 1.0 bf16

    f32x4 oacc[2][8] = {};   // 32q x 128m -> 64 f32/lane
    f32x4 lacc[2] = {};

    // staging: Ks 16KB = 16 chunks, Vt 16KB = 16 chunks; 4 of each per wave
    auto stage = [&](int buf, int jt) {
        const u16* Kg = Kg0 + (size_t)jt * 32 * 768;
        const u16* Vg = Hg0 + (size_t)jt * 32;
        #pragma unroll
        for (int i2 = 0; i2 < 4; ++i2) {
            int i = wu * 4 + i2;
            int c = i * 64 + lane;
            {   // Ks: 32 rows x 256 u16 (32 slots of 8)
                int row = c >> 5, p = c & 31, s = p ^ (row & 7);
                gll16(Kg + (size_t)row * 768 + s * 8, &Ks[buf][i * 512]);
            }
            {   // Vt: 256 rows x 32 u16 (4 slots of 8)
                int row = c >> 2, p = c & 3, s = p ^ ((row >> 1) & 3);
                gll16(Vg + (size_t)row * 2304 + s * 8, &Vt[buf][i * 512]);
            }
        }
    };

    stage(0, jq * 18);
    asm volatile("s_waitcnt vmcnt(0)");
    __syncthreads();
    int cur = 0;
    for (int it = 0; it < 18; ++it) {
        if (it + 1 < 18) stage(cur ^ 1, jq * 18 + it + 1);
        const u16* ks = &Ks[cur][0];
        const u16* vt = &Vt[cur][0];

        // QK^T: full 32 j for this wave's 32 q (wave-local; acc[fm][fj])
        __builtin_amdgcn_s_setprio(1);
        f32x4 acc[2][2] = {};
        #pragma unroll
        for (int kk = 0; kk < 8; ++kk) {
            bf16x8 kf0 = frag256(ks, l15,      kk * 4 + g);
            bf16x8 kf1 = frag256(ks, 16 + l15, kk * 4 + g);
            acc[0][0] = mfma16(qf[0][kk], kf0, acc[0][0]);
            acc[0][1] = mfma16(qf[0][kk], kf1, acc[0][1]);
            acc[1][0] = mfma16(qf[1][kk], kf0, acc[1][0]);
            acc[1][1] = mfma16(qf[1][kk], kf1, acc[1][1]);
        }
        __builtin_amdgcn_s_setprio(0);

        // P = exp2(S) -> wave-private Ps (swizzled [q][j], 32-u16 rows); no barrier
        #pragma unroll
        for (int fm = 0; fm < 2; ++fm)
            #pragma unroll
            for (int fj = 0; fj < 2; ++fj)
                #pragma unroll
                for (int r = 0; r < 4; ++r) {
                    int row = fm * 16 + 4 * g + r, col = fj * 16 + l15;
                    float p = exp2fast(acc[fm][fj][r]);
                    int sp = ((col >> 3) ^ ((row >> 1) & 3)) << 3;
                    Pw[row * 32 + sp + (col & 7)] = f2bf(p);
                }

        // PV: O[q][m] += P[q][j] * V^T[m][j]; l via ones-MFMA (all wave-local)
        __builtin_amdgcn_s_setprio(1);
        {
            bf16x8 pf0 = frag32(Pw, l15,      g);
            bf16x8 pf1 = frag32(Pw, 16 + l15, g);
            lacc[0] = mfma16(pf0, ones, lacc[0]);
            lacc[1] = mfma16(pf1, ones, lacc[1]);
            #pragma unroll
            for (int fn = 0; fn < 8; ++fn) {
                bf16x8 vv = frag32(vt, mh * 128 + fn * 16 + l15, g);
                oacc[0][fn] = mfma16(pf0, vv, oacc[0][fn]);
                oacc[1][fn] = mfma16(pf1, vv, oacc[1][fn]);
            }
        }
        __builtin_amdgcn_s_setprio(0);

        asm volatile("s_waitcnt vmcnt(0)");   // own prefetch of t+1 landed
        __syncthreads();                      // all waves done reading cur
        cur ^= 1;
    }

    // epilogue: normalized partial O (this wave's m-half) + l (mh==0 writes)
    const size_t prow0 = (size_t)jq * 16 * 2304 + (size_t)b * 2304 + qt * 64 + rg * 32;
    #pragma unroll
    for (int fm = 0; fm < 2; ++fm)
        #pragma unroll
        for (int r = 0; r < 4; ++r) {
            const int rl = fm * 16 + 4 * g + r;
            const float il = 1.0f / lacc[fm][r];
            #pragma unroll
            for (int fn = 0; fn < 8; ++fn)
                Opart[(prow0 + rl) * 256 + mh * 128 + fn * 16 + l15]
                    = f2bf(oacc[fm][fn][r] * il);
            if (mh == 0 && l15 == 0) statl[prow0 + rl] = lacc[fm][r];
        }
}

// ---------------------------------------------------------------- combine 4 j-quarters
__global__ __launch_bounds__(256) void k_comb(
    const u16* __restrict__ Opart, const float* __restrict__ statl,
    u16* __restrict__ O)
{
    const int tid = blockIdx.x * 256 + threadIdx.x;   // 36864*32 threads
    const int row = tid >> 5, c0 = (tid & 31) * 8;
    float l0 = statl[row],             l1 = statl[36864 + row];
    float l2 = statl[2 * 36864 + row], l3 = statl[3 * 36864 + row];
    const float inv = 1.0f / (l0 + l1 + l2 + l3);
    const float w0 = l0 * inv, w1 = l1 * inv, w2 = l2 * inv, w3 = l3 * inv;
    u16x8 a0 = *(const u16x8*)(Opart + ((size_t)0 * 36864 + row) * 256 + c0);
    u16x8 a1 = *(const u16x8*)(Opart + ((size_t)1 * 36864 + row) * 256 + c0);
    u16x8 a2 = *(const u16x8*)(Opart + ((size_t)2 * 36864 + row) * 256 + c0);
    u16x8 a3 = *(const u16x8*)(Opart + ((size_t)3 * 36864 + row) * 256 + c0);
    u16x8 o;
    #pragma unroll
    for (int e = 0; e < 8; ++e)
        o[e] = f2bf(bf2f(a0[e]) * w0 + bf2f(a1[e]) * w1 +
                    bf2f(a2[e]) * w2 + bf2f(a3[e]) * w3);
    *(u16x8*)(O + (size_t)row * 256 + c0) = o;
}

// ---------------------------------------------------------------- launch
extern "C" void kernel_launch(void* const* d_in, const int* in_sizes, int n_in,
                              void* d_out, int out_size, void* d_ws, size_t ws_size,
                              hipStream_t stream)
{
    const float* x   = (const float*)d_in[0];
    const float* Wf  = (const float*)d_in[1];
    const float* bfp = (const float*)d_in[2];
    const float* gf  = (const float*)d_in[3];
    const float* btf = (const float*)d_in[4];
    const float* mf  = (const float*)d_in[5];
    const float* vf  = (const float*)d_in[6];
    const float* Wg  = (const float*)d_in[7];
    const float* bg  = (const float*)d_in[8];
    const float* gg  = (const float*)d_in[9];
    const float* btg = (const float*)d_in[10];
    const float* mg  = (const float*)d_in[11];
    const float* vg  = (const float*)d_in[12];
    const float* Wh  = (const float*)d_in[13];
    const float* bh  = (const float*)d_in[14];
    const float* Wv  = (const float*)d_in[15];
    const float* bv  = (const float*)d_in[16];
    float* out = (float*)d_out;

    // workspace layout (~40.4 MB)
    char* ws = (char*)d_ws;
    float* statl = (float*)(ws + 0);           // [4][36864] f32 = 589824 B
    float* alpha = (float*)(ws + 589824);      // 3072 B
    float* beta  = (float*)(ws + 592896);      // 3072 B
    u16*   W3bf  = (u16*)  (ws + 595968);      // 1572864 B
    u16*   Wvbf  = (u16*)  (ws + 2168832);     // 524288 B
    u16*   O     = (u16*)  (ws + 2693120);     // 18874368 B
    u16*   HT    = (u16*)  (ws + 21567488);    // 18874368 B -> 40441856 total

    // d_out doubles as scratch until the final GEMM overwrites it:
    // Opart[4][16][2304][256] bf16 = 75497472 B == xT region (xT dead after gemm0)
    u16* xT    = (u16*)d_out;
    u16* Opart = (u16*)d_out;
    u16* FGH   = (u16*)((char*)d_out + 75497472);  // 56623104 B

    k_prep<<<dim3(4099), 256, 0, stream>>>(Wf, bfp, gf, btf, mf, vf, Wg, bg, gg, btg,
                                           mg, vg, Wh, bh, Wv, W3bf, Wvbf, alpha, beta);
    k_transpose<<<dim3(36, 16, 16), 256, 0, stream>>>(x, xT);
    k_gemm<0><<<dim3(288, 6, 1), 256, 0, stream>>>(xT, W3bf, 1024,
                                                   FGH, alpha, beta,
                                                   nullptr, nullptr, nullptr);
    k_htrans<<<dim3(36, 4, 16), 256, 0, stream>>>(FGH, HT);
    k_attn<<<dim3(36, 4, 16), 256, 0, stream>>>(FGH, HT, Opart, statl);
    k_comb<<<dim3(4608), 256, 0, stream>>>(Opart, statl, O);
    k_gemm<1><<<dim3(8, 18, 16), 256, 0, stream>>>(Wvbf, O, 256,
                                                   nullptr, nullptr, nullptr,
                                                   out, bv, x);
}

// Round 14
// 367.971 us; speedup vs baseline: 1.1770x; 1.1770x over previous
//
#include <hip/hip_runtime.h>
#include <stdint.h>

using u16 = unsigned short;
typedef u16   u16x8  __attribute__((ext_vector_type(8)));
typedef u16   u16x4  __attribute__((ext_vector_type(4)));
typedef short bf16x8 __attribute__((ext_vector_type(8)));
typedef float f32x4  __attribute__((ext_vector_type(4)));

#define DEVI static __device__ __forceinline__

// sizes (fixed): B=16, C=1024, HW=48*48=2304, MID=256, N3=768
// attention: JBLK=32, 72 j-tiles, 4 j-quarters of 18; q-tile 64

DEVI u16 f2bf(float f) {                       // RNE float->bf16
    union { float f; uint32_t u; } v; v.f = f;
    return (u16)((v.u + 0x7fffu + ((v.u >> 16) & 1u)) >> 16);
}
DEVI float bf2f(u16 u) {
    union { uint32_t u; float f; } v; v.u = (uint32_t)u << 16; return v.f;
}

DEVI f32x4 mfma16(bf16x8 a, bf16x8 b, f32x4 c) {
    return __builtin_amdgcn_mfma_f32_16x16x32_bf16(a, b, c, 0, 0, 0);
}

DEVI float exp2fast(float x) { return __builtin_amdgcn_exp2f(x); }

// async global->LDS, 16B per lane; LDS dest = wave-uniform base + lane*16
DEVI void gll16(const u16* g, u16* l) {
    __builtin_amdgcn_global_load_lds(
        (const __attribute__((address_space(1))) void*)g,
        (__attribute__((address_space(3))) void*)l, 16, 0, 0);
}

// LDS tile readers; layout: [row][8*spr u16], logical slot s stored at s^(row&7)
DEVI bf16x8 frag64(const u16* base, int row, int slot) {   // 64 u16 per row (8 slots)
    return *(const bf16x8*)(base + row * 64 + ((slot ^ (row & 7)) << 3));
}
DEVI bf16x8 frag256(const u16* base, int row, int slot) {  // 256 u16 per row (32 slots)
    return *(const bf16x8*)(base + row * 256 + ((slot ^ (row & 7)) << 3));
}
// 32-u16 rows (4 slots of 8): slot s stored at s^((row>>1)&3)
DEVI bf16x8 frag32(const u16* base, int row, int slot) {
    return *(const bf16x8*)(base + row * 32 + ((slot ^ ((row >> 1) & 3)) << 3));
}

// ---------------------------------------------------------------- prep
__global__ __launch_bounds__(256) void k_prep(
    const float* __restrict__ Wf, const float* __restrict__ bfp,
    const float* __restrict__ gf, const float* __restrict__ btf,
    const float* __restrict__ mf, const float* __restrict__ vf,
    const float* __restrict__ Wg, const float* __restrict__ bg,
    const float* __restrict__ gg, const float* __restrict__ btg,
    const float* __restrict__ mg, const float* __restrict__ vg,
    const float* __restrict__ Wh, const float* __restrict__ bh,
    const float* __restrict__ Wv,
    u16* __restrict__ W3bf, u16* __restrict__ Wvbf,
    float* __restrict__ alpha, float* __restrict__ beta)
{
    int tid = blockIdx.x * 256 + threadIdx.x;
    if (tid < 768 * 1024) {
        int n = tid >> 10, k = tid & 1023;
        float w = (n < 256) ? Wf[n * 1024 + k]
                : (n < 512) ? Wg[(n - 256) * 1024 + k]
                            : Wh[(n - 512) * 1024 + k];
        W3bf[tid] = f2bf(w);
    } else if (tid < 768 * 1024 + 256 * 1024) {
        int i = tid - 768 * 1024;
        Wvbf[i] = f2bf(Wv[i]);
    } else if (tid < 768 * 1024 + 256 * 1024 + 768) {
        int n = tid - (768 * 1024 + 256 * 1024);
        const float EPS = 1e-5f;
        const float SC  = 0.0625f * 1.4426950408889634f;  // mid^-0.5 * log2(e)
        float a, be;
        if (n < 256) {
            float inv = gf[n] / sqrtf(vf[n] + EPS);
            a  = inv * SC;
            be = (bfp[n] * inv + btf[n] - mf[n] * inv) * SC;
        } else if (n < 512) {
            int m = n - 256;
            float inv = gg[m] / sqrtf(vg[m] + EPS);
            a  = inv;
            be = bg[m] * inv + btg[m] - mg[m] * inv;
        } else { a = 1.0f; be = bh[n - 512]; }
        alpha[n] = a; beta[n] = be;
    }
}

// ---------------------------------------------------------------- x -> xT (bf16)
__global__ __launch_bounds__(256) void k_transpose(
    const float* __restrict__ x, u16* __restrict__ xT)
{
    __shared__ __align__(16) u16 tile[64 * 68];
    const int t  = threadIdx.x;
    const int it = blockIdx.x;   // 0..35
    const int ct = blockIdx.y;   // 0..15
    const int b  = blockIdx.z;   // 0..15
    const size_t xbase = ((size_t)(b * 1024 + ct * 64)) * 2304 + (size_t)it * 64;
    #pragma unroll
    for (int q = 0; q < 4; ++q) {
        int idx = q * 256 + t;
        int cl = idx >> 4, i4 = idx & 15;
        float4 v = *(const float4*)(x + xbase + (size_t)cl * 2304 + i4 * 4);
        tile[(i4 * 4 + 0) * 68 + cl] = f2bf(v.x);
        tile[(i4 * 4 + 1) * 68 + cl] = f2bf(v.y);
        tile[(i4 * 4 + 2) * 68 + cl] = f2bf(v.z);
        tile[(i4 * 4 + 3) * 68 + cl] = f2bf(v.w);
    }
    __syncthreads();
    const size_t obase = ((size_t)(b * 2304 + it * 64)) * 1024 + (size_t)ct * 64;
    #pragma unroll
    for (int q = 0; q < 4; ++q) {
        int idx = q * 256 + t;
        int il = idx >> 4, c4 = idx & 15;
        u16x4 w = *(const u16x4*)(&tile[il * 68 + c4 * 4]);
        *(u16x4*)(xT + obase + (size_t)il * 1024 + c4 * 4) = w;
    }
}

// ---------------------------------------------------------------- NT GEMM 128x128, BK=64
// double-buffered global_load_lds prefetch. MODE 0: fgh conv; n<512 -> BN/ReLU
// bf16 to FGH row-major; n>=512 (h-section) -> +bias then TRANSPOSED write to
// HT[b][m][i] via padded-LDS bounce (fuses the old k_htrans; FGH h-section never
// materialized). MODE 1: final conv, fp32 out + bias + residual.
template<int MODE>
__global__ __launch_bounds__(256) void k_gemm(
    const u16* __restrict__ A, const u16* __restrict__ Bm, const int K,
    u16* __restrict__ Cbf, const float* __restrict__ alpha, const float* __restrict__ beta,
    u16* __restrict__ HTout,
    float* __restrict__ Cf, const float* __restrict__ bias, const float* __restrict__ resid)
{
    __shared__ __align__(16) u16 smem[32768];   // 64 KB: As[2][8192] | Bs[2][8192]
    u16* As0 = smem;           // [2][128*64]
    u16* Bs0 = smem + 16384;
    const int t = threadIdx.x;
    const int lane = t & 63, wave = t >> 6;
    const int wu = __builtin_amdgcn_readfirstlane(wave);
    const int g = lane >> 4, l15 = lane & 15;
    const int wr = wave >> 1, wc = wave & 1;
    const int m0 = blockIdx.x * 128, n0 = blockIdx.y * 128;
    const int b  = blockIdx.z;

    const u16* Ag = A + (size_t)m0 * K;
    const u16* Bg = (MODE == 0) ? (Bm + (size_t)n0 * K)
                                : (Bm + ((size_t)b * 2304 + n0) * K);

    auto stage = [&](int buf, int ks) {
        #pragma unroll
        for (int i = 0; i < 4; ++i) {
            int c = i * 256 + wu * 64 + lane;
            int row = c >> 3, p = c & 7, s = p ^ (row & 7);
            size_t go = (size_t)row * K + ks * 64 + s * 8;
            gll16(Ag + go, As0 + buf * 8192 + (i * 256 + wu * 64) * 8);
            gll16(Bg + go, Bs0 + buf * 8192 + (i * 256 + wu * 64) * 8);
        }
    };

    f32x4 acc[4][4] = {};
    const int nks = K >> 6;
    stage(0, 0);
    asm volatile("s_waitcnt vmcnt(0)");
    __syncthreads();
    int cur = 0;
    for (int ks = 0; ks < nks; ++ks) {
        if (ks + 1 < nks) stage(cur ^ 1, ks + 1);
        const u16* as = As0 + cur * 8192;
        const u16* bs = Bs0 + cur * 8192;
        __builtin_amdgcn_s_setprio(1);
        #pragma unroll
        for (int kk = 0; kk < 2; ++kk) {
            const int slot = kk * 4 + g;
            bf16x8 af[4], bfv[4];
            #pragma unroll
            for (int f = 0; f < 4; ++f) af[f]  = frag64(as, wr * 64 + f * 16 + l15, slot);
            #pragma unroll
            for (int f = 0; f < 4; ++f) bfv[f] = frag64(bs, wc * 64 + f * 16 + l15, slot);
            #pragma unroll
            for (int fm = 0; fm < 4; ++fm)
                #pragma unroll
                for (int fn = 0; fn < 4; ++fn)
                    acc[fm][fn] = mfma16(af[fm], bfv[fn], acc[fm][fn]);
        }
        __builtin_amdgcn_s_setprio(0);
        asm volatile("s_waitcnt vmcnt(0)");
        __syncthreads();
        cur ^= 1;
    }

    if (MODE == 0) {
        if (n0 < 512) {
            // f/g sections: BN + ReLU, row-major bf16 into FGH (768-wide rows)
            #pragma unroll
            for (int fn = 0; fn < 4; ++fn) {
                const int n = n0 + wc * 64 + fn * 16 + l15;
                const float al = alpha[n], be = beta[n];
                #pragma unroll
                for (int fm = 0; fm < 4; ++fm)
                    #pragma unroll
                    for (int r = 0; r < 4; ++r) {
                        const int row = m0 + wr * 64 + fm * 16 + 4 * g + r;
                        float y = fmaxf(acc[fm][fn][r] * al + be, 0.0f);
                        Cbf[(size_t)row * 768 + n] = f2bf(y);
                    }
            }
        } else {
            // h-section: +bias, transposed write to HT[b][m][i] via LDS bounce
            const int b2 = m0 / 2304, i0 = m0 % 2304;     // 2304 = 18*128
            u16* tile = smem;                             // [128][136] padded
            #pragma unroll
            for (int fn = 0; fn < 4; ++fn) {
                const int n = n0 + wc * 64 + fn * 16 + l15;
                const float al = alpha[n], be = beta[n];
                const int nl = wc * 64 + fn * 16 + l15;
                #pragma unroll
                for (int fm = 0; fm < 4; ++fm)
                    #pragma unroll
                    for (int r = 0; r < 4; ++r) {
                        const int il = wr * 64 + fm * 16 + 4 * g + r;
                        tile[nl * 136 + il] = f2bf(acc[fm][fn][r] * al + be);
                    }
            }
            __syncthreads();
            #pragma unroll
            for (int qq = 0; qq < 16; ++qq) {
                int idx = qq * 256 + t;
                int nl = idx >> 5, c4 = (idx & 31) * 4;
                u16x4 w = *(const u16x4*)(&tile[nl * 136 + c4]);
                *(u16x4*)(HTout + ((size_t)(b2 * 256 + (n0 - 512) + nl)) * 2304
                          + i0 + c4) = w;
            }
        }
    } else {
        const size_t ob = (size_t)b * 1024 * 2304;
        #pragma unroll
        for (int fm = 0; fm < 4; ++fm)
            #pragma unroll
            for (int r = 0; r < 4; ++r) {
                const int row = m0 + wr * 64 + fm * 16 + 4 * g + r;   // c
                const float bb = bias[row];
                #pragma unroll
                for (int fn = 0; fn < 4; ++fn) {
                    const int n = n0 + wc * 64 + fn * 16 + l15;        // i
                    const size_t o = ob + (size_t)row * 2304 + n;
                    Cf[o] = acc[fm][fn][r] + bb + resid[o];
                }
            }
    }
}

// ---------------------------------------------------------------- fused attention v4 (r12 best)
// grid (qt=36, jq=4, b=16); 4 waves = 2 row-groups (rg, 32q) x 2 m-halves (mh, 128m).
// QK split by j-half between mh twins (P exchanged via per-rg LDS tile + barrier);
// PV reads full 32-j P rows. Two independent blocks co-resident per CU.
// No-max softmax (anchor 0), row-sum via ones-MFMA, dbuf K/V prefetch.
// r13 lesson: wave-local QK (barrier removal) doubles kf reads + bank conflicts
// and REGRESSES — LDS ops are the binding resource here; keep the barrier.
// NOTE: single-arg launch_bounds — second arg N caps VGPRs at 256/N (r2/r3 spills).
__global__ __launch_bounds__(256) void k_attn(
    const u16* __restrict__ FGH, const u16* __restrict__ HT,
    u16* __restrict__ Opart, float* __restrict__ statl)
{
    __shared__ __align__(16) u16 Ks[2][32 * 256];   // 2x16 KB [j][k]
    __shared__ __align__(16) u16 Vt[2][256 * 32];   // 2x16 KB [m][j]
    __shared__ __align__(16) u16 Ps[2][32 * 32];    //   4 KB per-rg P (32q x 32j)
    const int t = threadIdx.x;
    const int lane = t & 63, wave = t >> 6;
    const int wu = __builtin_amdgcn_readfirstlane(wave);
    const int rg = wu >> 1, mh = wu & 1;
    const int g = lane >> 4, l15 = lane & 15;
    const int qt = blockIdx.x, jq = blockIdx.y, b = blockIdx.z;

    // Q rows of this wave: qt*64 + rg*32 + fm*16 + l15
    const u16* Qg = FGH + ((size_t)b * 2304 + qt * 64 + rg * 32) * 768;
    bf16x8 qf[2][8];
    #pragma unroll
    for (int fm = 0; fm < 2; ++fm)
        #pragma unroll
        for (int kk = 0; kk < 8; ++kk)
            qf[fm][kk] = *(const bf16x8*)(Qg + (size_t)(fm * 16 + l15) * 768 + kk * 32 + g * 8);

    const u16* Kg0 = FGH + (size_t)b * 2304 * 768 + 256;   // keys [j][k]
    const u16* Hg0 = HT + (size_t)b * 256 * 2304;          // V^T [m][j]
    u16* Pw = &Ps[rg][0];

    bf16x8 ones;
    #pragma unroll
    for (int e = 0; e < 8; ++e) ones[e] = (short)0x3F80;   // 1.0 bf16

    f32x4 oacc[2][8] = {};   // 32q x 128m -> 64 f32/lane
    f32x4 lacc[2] = {};

    // staging: Ks 16KB = 16 chunks, Vt 16KB = 16 chunks; 4 of each per wave
    auto stage = [&](int buf, int jt) {
        const u16* Kg = Kg0 + (size_t)jt * 32 * 768;
        const u16* Vg = Hg0 + (size_t)jt * 32;
        #pragma unroll
        for (int i2 = 0; i2 < 4; ++i2) {
            int i = wu * 4 + i2;
            int c = i * 64 + lane;
            {   // Ks: 32 rows x 256 u16 (32 slots of 8)
                int row = c >> 5, p = c & 31, s = p ^ (row & 7);
                gll16(Kg + (size_t)row * 768 + s * 8, &Ks[buf][i * 512]);
            }
            {   // Vt: 256 rows x 32 u16 (4 slots of 8)
                int row = c >> 2, p = c & 3, s = p ^ ((row >> 1) & 3);
                gll16(Vg + (size_t)row * 2304 + s * 8, &Vt[buf][i * 512]);
            }
        }
    };

    stage(0, jq * 18);
    asm volatile("s_waitcnt vmcnt(0)");
    __syncthreads();
    int cur = 0;
    for (int it = 0; it < 18; ++it) {
        if (it + 1 < 18) stage(cur ^ 1, jq * 18 + it + 1);
        const u16* ks = &Ks[cur][0];
        const u16* vt = &Vt[cur][0];

        // QK^T for this wave's j-half (j = mh*16 + l15), rows fm*16+4g+r
        __builtin_amdgcn_s_setprio(1);
        f32x4 acc[2] = {};
        #pragma unroll
        for (int kk = 0; kk < 8; ++kk) {
            bf16x8 kf = frag256(ks, mh * 16 + l15, kk * 4 + g);
            acc[0] = mfma16(qf[0][kk], kf, acc[0]);
            acc[1] = mfma16(qf[1][kk], kf, acc[1]);
        }
        __builtin_amdgcn_s_setprio(0);

        // P = exp2(S) -> Ps[rg] (swizzled [q][j], 32-u16 rows)
        #pragma unroll
        for (int fm = 0; fm < 2; ++fm)
            #pragma unroll
            for (int r = 0; r < 4; ++r) {
                int row = fm * 16 + 4 * g + r, col = mh * 16 + l15;
                float p = exp2fast(acc[fm][r]);
                int sp = ((col >> 3) ^ ((row >> 1) & 3)) << 3;
                Pw[row * 32 + sp + (col & 7)] = f2bf(p);
            }
        __syncthreads();   // Ps complete across mh twins

        // PV: O[q][m] += P[q][j] * V^T[m][j]; l via ones-MFMA
        __builtin_amdgcn_s_setprio(1);
        {
            bf16x8 pf0 = frag32(Pw, l15,      g);
            bf16x8 pf1 = frag32(Pw, 16 + l15, g);
            lacc[0] = mfma16(pf0, ones, lacc[0]);
            lacc[1] = mfma16(pf1, ones, lacc[1]);
            #pragma unroll
            for (int fn = 0; fn < 8; ++fn) {
                bf16x8 vv = frag32(vt, mh * 128 + fn * 16 + l15, g);
                oacc[0][fn] = mfma16(pf0, vv, oacc[0][fn]);
                oacc[1][fn] = mfma16(pf1, vv, oacc[1][fn]);
            }
        }
        __builtin_amdgcn_s_setprio(0);

        asm volatile("s_waitcnt vmcnt(0)");   // prefetch of t+1 landed
        __syncthreads();                      // all reads of cur + Ps done
        cur ^= 1;
    }

    // epilogue: normalized partial O (this wave's m-half) + l (mh==0 writes)
    const size_t prow0 = (size_t)jq * 16 * 2304 + (size_t)b * 2304 + qt * 64 + rg * 32;
    #pragma unroll
    for (int fm = 0; fm < 2; ++fm)
        #pragma unroll
        for (int r = 0; r < 4; ++r) {
            const int rl = fm * 16 + 4 * g + r;
            const float il = 1.0f / lacc[fm][r];
            #pragma unroll
            for (int fn = 0; fn < 8; ++fn)
                Opart[(prow0 + rl) * 256 + mh * 128 + fn * 16 + l15]
                    = f2bf(oacc[fm][fn][r] * il);
            if (mh == 0 && l15 == 0) statl[prow0 + rl] = lacc[fm][r];
        }
}

// ---------------------------------------------------------------- combine 4 j-quarters
__global__ __launch_bounds__(256) void k_comb(
    const u16* __restrict__ Opart, const float* __restrict__ statl,
    u16* __restrict__ O)
{
    const int tid = blockIdx.x * 256 + threadIdx.x;   // 36864*32 threads
    const int row = tid >> 5, c0 = (tid & 31) * 8;
    float l0 = statl[row],             l1 = statl[36864 + row];
    float l2 = statl[2 * 36864 + row], l3 = statl[3 * 36864 + row];
    const float inv = 1.0f / (l0 + l1 + l2 + l3);
    const float w0 = l0 * inv, w1 = l1 * inv, w2 = l2 * inv, w3 = l3 * inv;
    u16x8 a0 = *(const u16x8*)(Opart + ((size_t)0 * 36864 + row) * 256 + c0);
    u16x8 a1 = *(const u16x8*)(Opart + ((size_t)1 * 36864 + row) * 256 + c0);
    u16x8 a2 = *(const u16x8*)(Opart + ((size_t)2 * 36864 + row) * 256 + c0);
    u16x8 a3 = *(const u16x8*)(Opart + ((size_t)3 * 36864 + row) * 256 + c0);
    u16x8 o;
    #pragma unroll
    for (int e = 0; e < 8; ++e)
        o[e] = f2bf(bf2f(a0[e]) * w0 + bf2f(a1[e]) * w1 +
                    bf2f(a2[e]) * w2 + bf2f(a3[e]) * w3);
    *(u16x8*)(O + (size_t)row * 256 + c0) = o;
}

// ---------------------------------------------------------------- launch
extern "C" void kernel_launch(void* const* d_in, const int* in_sizes, int n_in,
                              void* d_out, int out_size, void* d_ws, size_t ws_size,
                              hipStream_t stream)
{
    const float* x   = (const float*)d_in[0];
    const float* Wf  = (const float*)d_in[1];
    const float* bfp = (const float*)d_in[2];
    const float* gf  = (const float*)d_in[3];
    const float* btf = (const float*)d_in[4];
    const float* mf  = (const float*)d_in[5];
    const float* vf  = (const float*)d_in[6];
    const float* Wg  = (const float*)d_in[7];
    const float* bg  = (const float*)d_in[8];
    const float* gg  = (const float*)d_in[9];
    const float* btg = (const float*)d_in[10];
    const float* mg  = (const float*)d_in[11];
    const float* vg  = (const float*)d_in[12];
    const float* Wh  = (const float*)d_in[13];
    const float* bh  = (const float*)d_in[14];
    const float* Wv  = (const float*)d_in[15];
    const float* bv  = (const float*)d_in[16];
    float* out = (float*)d_out;

    // workspace layout (~40.4 MB)
    char* ws = (char*)d_ws;
    float* statl = (float*)(ws + 0);           // [4][36864] f32 = 589824 B
    float* alpha = (float*)(ws + 589824);      // 3072 B
    float* beta  = (float*)(ws + 592896);      // 3072 B
    u16*   W3bf  = (u16*)  (ws + 595968);      // 1572864 B
    u16*   Wvbf  = (u16*)  (ws + 2168832);     // 524288 B
    u16*   O     = (u16*)  (ws + 2693120);     // 18874368 B
    u16*   HT    = (u16*)  (ws + 21567488);    // 18874368 B -> 40441856 total

    // d_out doubles as scratch until the final GEMM overwrites it:
    // Opart[4][16][2304][256] bf16 = 75497472 B == xT region (xT dead after gemm0)
    u16* xT    = (u16*)d_out;
    u16* Opart = (u16*)d_out;
    u16* FGH   = (u16*)((char*)d_out + 75497472);  // 56623104 B (f/g sections used)

    k_prep<<<dim3(4099), 256, 0, stream>>>(Wf, bfp, gf, btf, mf, vf, Wg, bg, gg, btg,
                                           mg, vg, Wh, bh, Wv, W3bf, Wvbf, alpha, beta);
    k_transpose<<<dim3(36, 16, 16), 256, 0, stream>>>(x, xT);
    k_gemm<0><<<dim3(288, 6, 1), 256, 0, stream>>>(xT, W3bf, 1024,
                                                   FGH, alpha, beta, HT,
                                                   nullptr, nullptr, nullptr);
    k_attn<<<dim3(36, 4, 16), 256, 0, stream>>>(FGH, HT, Opart, statl);
    k_comb<<<dim3(4608), 256, 0, stream>>>(Opart, statl, O);
    k_gemm<1><<<dim3(8, 18, 16), 256, 0, stream>>>(Wvbf, O, 256,
                                                   nullptr, nullptr, nullptr, nullptr,
                                                   out, bv, x);
}